// Round 9
// baseline (172.136 us; speedup 1.0000x reference)
//
#include <hip/hip_runtime.h>
#include <math.h>

#define NB   16
#define NN   307
#define MPAD 308          // padded m for G rows
#define Q4   77           // MPAD/4: m-tiles of 4
#define KCH  3
#define IND  66           // INPUT_DIM + HIDDEN
#define KI   198          // KCH * IND
#define HID  64
#define HG   128          // 2 * HIDDEN

typedef float f32x4 __attribute__((ext_vector_type(4)));

// ws layout (floats)
#define OFF_GP  0
#define SZ_GP   (KCH * NN * MPAD)         // 283,668
#define OFF_X1  (OFF_GP + SZ_GP)
#define SZ_X    (NB * Q4 * IND * 4)       // 325,248  x tiled: [b][q][i][e], m = 4q+e
#define OFF_X2  (OFF_X1 + SZ_X)
#define OFF_Z   (OFF_X2 + SZ_X)
#define SZ_X2I  (NB * Q4 * 2 * 4)         // x2 xt-row init elements (i<2 only)

// K0: padded G copy [k][n][m(308)]; x1 = combined tiled [b][q][i][e];
//     x2: only i<2 rows (xt) written — i>=2 rows written by gate each call,
//     and m-pad elements always multiply G_p zeros (exact 0 contribution).
__global__ void prep_kernel(const float* __restrict__ G,
                            const float* __restrict__ xt,
                            const float* __restrict__ h,
                            float* __restrict__ G_p,
                            float* __restrict__ x1,
                            float* __restrict__ x2) {
    int idx = blockIdx.x * blockDim.x + threadIdx.x;
    if (idx < SZ_GP) {
        int mp = idx % MPAD;
        int kn = idx / MPAD;
        G_p[idx] = (mp < NN) ? G[kn * NN + mp] : 0.f;
    } else if (idx < SZ_GP + SZ_X) {
        int j = idx - SZ_GP;
        int e = j & 3;
        int t = j >> 2;
        int i = t % IND;
        int q = (t / IND) % Q4;
        int b = t / (IND * Q4);
        int m = q * 4 + e;
        float v = 0.f;
        if (m < NN)
            v = (i < 2) ? xt[(b * NN + m) * 2 + i]
                        : h[(b * NN + m) * HID + (i - 2)];
        x1[j] = v;
    } else if (idx < SZ_GP + SZ_X + SZ_X2I) {
        int j = idx - SZ_GP - SZ_X;
        int e  = j & 3;
        int t  = j >> 2;
        int i  = t & 1;
        int t2 = t >> 1;
        int q  = t2 % Q4;
        int b  = t2 / Q4;
        int m  = q * 4 + e;
        float v = (m < NN) ? xt[(b * NN + m) * 2 + i] : 0.f;
        x2[(((size_t)b * Q4 + q) * IND + i) * 4 + e] = v;
    }
}

// K1: fused gcn1 + gate with W-prefetch interleaved into phase-1.
__global__ __launch_bounds__(128) void gate_fused(const float* __restrict__ G_p,
                                                  const float* __restrict__ xT,
                                                  const float* __restrict__ W,
                                                  const float* __restrict__ bias,
                                                  const float* __restrict__ h,
                                                  float* __restrict__ z_out,
                                                  float* __restrict__ xT2) {
    __shared__ float s[KI];
    __shared__ float red[4][HG];
    const int bn  = blockIdx.x;
    const int b   = bn / NN;
    const int n   = bn % NN;
    const int tid = threadIdx.x;
    const int r   = tid >> 5;
    const int c4  = (tid & 31) * 4;
    const f32x4* Wp = (const f32x4*)(W + (size_t)bn * KI * HG + c4);
    // ---- phase 1 (branchless; lanes >= IND compute a discarded dummy row) ----
    const int ii = (tid < IND) ? tid : 0;
    const f32x4* xp = (const f32x4*)xT + (size_t)b * (Q4 * IND) + ii;
    const f32x4* gp = (const f32x4*)G_p + (size_t)n * Q4;
    f32x4 a0 = {0.f, 0.f, 0.f, 0.f}, a1 = a0, a2 = a0;
    f32x4 w0, w1, w2, w3, w4, w5, w6, w7, w8, w9;
    #pragma unroll
    for (int q = 0; q < Q4; ++q) {
        if (q == 0)  w0 = __builtin_nontemporal_load(Wp + (size_t)(r +  0) * (HG / 4));
        if (q == 8)  w1 = __builtin_nontemporal_load(Wp + (size_t)(r +  4) * (HG / 4));
        if (q == 16) w2 = __builtin_nontemporal_load(Wp + (size_t)(r +  8) * (HG / 4));
        if (q == 24) w3 = __builtin_nontemporal_load(Wp + (size_t)(r + 12) * (HG / 4));
        if (q == 32) w4 = __builtin_nontemporal_load(Wp + (size_t)(r + 16) * (HG / 4));
        if (q == 40) w5 = __builtin_nontemporal_load(Wp + (size_t)(r + 20) * (HG / 4));
        if (q == 48) w6 = __builtin_nontemporal_load(Wp + (size_t)(r + 24) * (HG / 4));
        if (q == 56) w7 = __builtin_nontemporal_load(Wp + (size_t)(r + 28) * (HG / 4));
        if (q == 64) w8 = __builtin_nontemporal_load(Wp + (size_t)(r + 32) * (HG / 4));
        if (q == 72) w9 = __builtin_nontemporal_load(Wp + (size_t)(r + 36) * (HG / 4));
        f32x4 xv = xp[(size_t)q * IND];           // coalesced across lanes
        a0 += xv * gp[q];                          // wave-uniform broadcasts
        a1 += xv * gp[q + (size_t)NN * Q4];
        a2 += xv * gp[q + (size_t)2 * NN * Q4];
    }
    if (tid < IND) {
        s[tid]           = a0.x + a0.y + a0.z + a0.w;
        s[IND + tid]     = a1.x + a1.y + a1.z + a1.w;
        s[2 * IND + tid] = a2.x + a2.y + a2.z + a2.w;
    }
    __syncthreads();
    // ---- phase 2: consume prefetch, continue W stream ----
    float4 acc = make_float4(0.f, 0.f, 0.f, 0.f);
#define CONS(wv, I) { float sv = s[(I)]; acc.x += sv * (wv).x; acc.y += sv * (wv).y; \
                      acc.z += sv * (wv).z; acc.w += sv * (wv).w; }
    CONS(w0, r)      CONS(w1, r + 4)  CONS(w2, r + 8)  CONS(w3, r + 12)
    CONS(w4, r + 16) CONS(w5, r + 20) CONS(w6, r + 24) CONS(w7, r + 28)
    CONS(w8, r + 32) CONS(w9, r + 36)
    #pragma unroll 8
    for (int i = r + 40; i < KI; i += 4) {
        f32x4 w = __builtin_nontemporal_load(Wp + (size_t)i * (HG / 4));
        float sv = s[i];
        acc.x += sv * w.x; acc.y += sv * w.y;
        acc.z += sv * w.z; acc.w += sv * w.w;
    }
#undef CONS
    red[r][c4 + 0] = acc.x; red[r][c4 + 1] = acc.y;
    red[r][c4 + 2] = acc.z; red[r][c4 + 3] = acc.w;
    __syncthreads();
    float a = bias[bn * HG + tid] + red[0][tid] + red[1][tid] + red[2][tid] + red[3][tid];
    float g = 1.0f / (1.0f + expf(-a));
    if (tid < HID) {
        z_out[bn * HID + tid] = g;                    // z
    } else {
        int hh = tid - HID;                           // r gate -> candidate elem at m=n
        int q = n >> 2, e = n & 3;
        xT2[(((size_t)b * Q4 + q) * IND + 2 + hh) * 4 + e] = g * h[bn * HID + hh];
    }
}

// K2: fused gcn2 + update with W-prefetch interleaved into phase-1.
__global__ __launch_bounds__(128) void update_fused(const float* __restrict__ G_p,
                                                    const float* __restrict__ xT2,
                                                    const float* __restrict__ W,
                                                    const float* __restrict__ bias,
                                                    const float* __restrict__ z,
                                                    const float* __restrict__ h,
                                                    float* __restrict__ out) {
    __shared__ float s[KI];
    __shared__ float red[8][HID];
    const int bn  = blockIdx.x;
    const int b   = bn / NN;
    const int n   = bn % NN;
    const int tid = threadIdx.x;
    const int r   = tid >> 4;
    const int c4  = (tid & 15) * 4;
    const f32x4* Wp = (const f32x4*)(W + (size_t)bn * KI * HID + c4);
    // ---- phase 1 ----
    const int ii = (tid < IND) ? tid : 0;
    const f32x4* xp = (const f32x4*)xT2 + (size_t)b * (Q4 * IND) + ii;
    const f32x4* gp = (const f32x4*)G_p + (size_t)n * Q4;
    f32x4 a0 = {0.f, 0.f, 0.f, 0.f}, a1 = a0, a2 = a0;
    f32x4 w0, w1, w2, w3, w4, w5, w6, w7, w8, w9;
    #pragma unroll
    for (int q = 0; q < Q4; ++q) {
        if (q == 0)  w0 = __builtin_nontemporal_load(Wp + (size_t)(r +  0) * (HID / 4));
        if (q == 8)  w1 = __builtin_nontemporal_load(Wp + (size_t)(r +  8) * (HID / 4));
        if (q == 16) w2 = __builtin_nontemporal_load(Wp + (size_t)(r + 16) * (HID / 4));
        if (q == 24) w3 = __builtin_nontemporal_load(Wp + (size_t)(r + 24) * (HID / 4));
        if (q == 32) w4 = __builtin_nontemporal_load(Wp + (size_t)(r + 32) * (HID / 4));
        if (q == 40) w5 = __builtin_nontemporal_load(Wp + (size_t)(r + 40) * (HID / 4));
        if (q == 48) w6 = __builtin_nontemporal_load(Wp + (size_t)(r + 48) * (HID / 4));
        if (q == 56) w7 = __builtin_nontemporal_load(Wp + (size_t)(r + 56) * (HID / 4));
        if (q == 64) w8 = __builtin_nontemporal_load(Wp + (size_t)(r + 64) * (HID / 4));
        if (q == 72) w9 = __builtin_nontemporal_load(Wp + (size_t)(r + 72) * (HID / 4));
        f32x4 xv = xp[(size_t)q * IND];
        a0 += xv * gp[q];
        a1 += xv * gp[q + (size_t)NN * Q4];
        a2 += xv * gp[q + (size_t)2 * NN * Q4];
    }
    if (tid < IND) {
        s[tid]           = a0.x + a0.y + a0.z + a0.w;
        s[IND + tid]     = a1.x + a1.y + a1.z + a1.w;
        s[2 * IND + tid] = a2.x + a2.y + a2.z + a2.w;
    }
    __syncthreads();
    // ---- phase 2 ----
    float4 acc = make_float4(0.f, 0.f, 0.f, 0.f);
#define CONS(wv, I) { float sv = s[(I)]; acc.x += sv * (wv).x; acc.y += sv * (wv).y; \
                      acc.z += sv * (wv).z; acc.w += sv * (wv).w; }
    CONS(w0, r)      CONS(w1, r + 8)  CONS(w2, r + 16) CONS(w3, r + 24)
    CONS(w4, r + 32) CONS(w5, r + 40) CONS(w6, r + 48) CONS(w7, r + 56)
    CONS(w8, r + 64) CONS(w9, r + 72)
    #pragma unroll 8
    for (int i = r + 80; i < KI; i += 8) {
        f32x4 w = __builtin_nontemporal_load(Wp + (size_t)i * (HID / 4));
        float sv = s[i];
        acc.x += sv * w.x; acc.y += sv * w.y;
        acc.z += sv * w.z; acc.w += sv * w.w;
    }
#undef CONS
    red[r][c4 + 0] = acc.x; red[r][c4 + 1] = acc.y;
    red[r][c4 + 2] = acc.z; red[r][c4 + 3] = acc.w;
    __syncthreads();
    if (tid < HID) {
        float a = bias[bn * HID + tid];
        #pragma unroll
        for (int rr = 0; rr < 8; ++rr) a += red[rr][tid];
        float nn = tanhf(a);
        float zz = z[bn * HID + tid];
        float hv = h[bn * HID + tid];
        out[bn * HID + tid] = zz * nn + (1.f - zz) * hv;
    }
}

extern "C" void kernel_launch(void* const* d_in, const int* in_sizes, int n_in,
                              void* d_out, int out_size, void* d_ws, size_t ws_size,
                              hipStream_t stream) {
    const float* G  = (const float*)d_in[0];
    const float* xt = (const float*)d_in[1];
    const float* h  = (const float*)d_in[2];
    const float* Wg = (const float*)d_in[3];
    const float* bg = (const float*)d_in[4];
    const float* Wu = (const float*)d_in[5];
    const float* bu = (const float*)d_in[6];
    float* out = (float*)d_out;

    float* ws   = (float*)d_ws;
    float* G_p  = ws + OFF_GP;
    float* x1   = ws + OFF_X1;
    float* x2   = ws + OFF_X2;
    float* z    = ws + OFF_Z;

    const int totPrep = SZ_GP + SZ_X + SZ_X2I;
    prep_kernel<<<(totPrep + 255) / 256, 256, 0, stream>>>(G, xt, h, G_p, x1, x2);

    gate_fused<<<NB * NN, 128, 0, stream>>>(G_p, x1, Wg, bg, h, z, x2);

    update_fused<<<NB * NN, 128, 0, stream>>>(G_p, x2, Wu, bu, z, h, out);
}

// Round 10
// 166.845 us; speedup vs baseline: 1.0317x; 1.0317x over previous
//
#include <hip/hip_runtime.h>
#include <math.h>

#define NB   16
#define NN   307
#define MPAD 308          // padded m for G rows
#define Q4   77           // MPAD/4: m-tiles of 4
#define KCH  3
#define IND  66           // INPUT_DIM + HIDDEN
#define KI   198          // KCH * IND
#define HID  64
#define HG   128          // 2 * HIDDEN

typedef float f32x4 __attribute__((ext_vector_type(4)));

// ws layout (floats)
#define OFF_GP  0
#define SZ_GP   (KCH * NN * MPAD)         // 283,668
#define OFF_X1  (OFF_GP + SZ_GP)
#define SZ_X    (NB * Q4 * IND * 4)       // 325,248  x tiled: [b][q][i][e], m = 4q+e
#define OFF_X2  (OFF_X1 + SZ_X)
#define OFF_Z   (OFF_X2 + SZ_X)
#define SZ_X2I  (NB * Q4 * 2 * 4)         // x2 xt-row init elements (i<2 only)

// K0: padded G copy [k][n][m(308)]; x1 = combined tiled [b][q][i][e];
//     x2: only i<2 rows (xt) written — i>=2 rows written by gate each call,
//     m-pad elements multiply G_p zeros (exact 0 contribution).
__global__ void prep_kernel(const float* __restrict__ G,
                            const float* __restrict__ xt,
                            const float* __restrict__ h,
                            float* __restrict__ G_p,
                            float* __restrict__ x1,
                            float* __restrict__ x2) {
    int idx = blockIdx.x * blockDim.x + threadIdx.x;
    if (idx < SZ_GP) {
        int mp = idx % MPAD;
        int kn = idx / MPAD;
        G_p[idx] = (mp < NN) ? G[kn * NN + mp] : 0.f;
    } else if (idx < SZ_GP + SZ_X) {
        int j = idx - SZ_GP;
        int e = j & 3;
        int t = j >> 2;
        int i = t % IND;
        int q = (t / IND) % Q4;
        int b = t / (IND * Q4);
        int m = q * 4 + e;
        float v = 0.f;
        if (m < NN)
            v = (i < 2) ? xt[(b * NN + m) * 2 + i]
                        : h[(b * NN + m) * HID + (i - 2)];
        x1[j] = v;
    } else if (idx < SZ_GP + SZ_X + SZ_X2I) {
        int j = idx - SZ_GP - SZ_X;
        int e  = j & 3;
        int t  = j >> 2;
        int i  = t & 1;
        int t2 = t >> 1;
        int q  = t2 % Q4;
        int b  = t2 / Q4;
        int m  = q * 4 + e;
        float v = (m < NN) ? xt[(b * NN + m) * 2 + i] : 0.f;
        x2[(((size_t)b * Q4 + q) * IND + i) * 4 + e] = v;
    }
}

// K1: fused gcn1 + gate. W-prefetch issued up-front (async), guarded phase-1,
//     then W stream.
__global__ __launch_bounds__(128) void gate_fused(const float* __restrict__ G_p,
                                                  const float* __restrict__ xT,
                                                  const float* __restrict__ W,
                                                  const float* __restrict__ bias,
                                                  const float* __restrict__ h,
                                                  float* __restrict__ z_out,
                                                  float* __restrict__ xT2) {
    __shared__ float s[KI];
    __shared__ float red[4][HG];
    const int bn  = blockIdx.x;
    const int b   = bn / NN;
    const int n   = bn % NN;
    const int tid = threadIdx.x;
    const int r   = tid >> 5;
    const int c4  = (tid & 31) * 4;
    const f32x4* Wp = (const f32x4*)(W + (size_t)bn * KI * HG + c4);
    // ---- issue W prefetch: 10 x 16B per thread, in flight during phase-1 ----
    f32x4 w0 = __builtin_nontemporal_load(Wp + (size_t)(r +  0) * (HG / 4));
    f32x4 w1 = __builtin_nontemporal_load(Wp + (size_t)(r +  4) * (HG / 4));
    f32x4 w2 = __builtin_nontemporal_load(Wp + (size_t)(r +  8) * (HG / 4));
    f32x4 w3 = __builtin_nontemporal_load(Wp + (size_t)(r + 12) * (HG / 4));
    f32x4 w4 = __builtin_nontemporal_load(Wp + (size_t)(r + 16) * (HG / 4));
    f32x4 w5 = __builtin_nontemporal_load(Wp + (size_t)(r + 20) * (HG / 4));
    f32x4 w6 = __builtin_nontemporal_load(Wp + (size_t)(r + 24) * (HG / 4));
    f32x4 w7 = __builtin_nontemporal_load(Wp + (size_t)(r + 28) * (HG / 4));
    f32x4 w8 = __builtin_nontemporal_load(Wp + (size_t)(r + 32) * (HG / 4));
    f32x4 w9 = __builtin_nontemporal_load(Wp + (size_t)(r + 36) * (HG / 4));
    // ---- phase 1 (guarded: only 66 lanes touch x/G) ----
    if (tid < IND) {
        const f32x4* xp = (const f32x4*)xT + (size_t)b * (Q4 * IND) + tid;
        const f32x4* gp = (const f32x4*)G_p + (size_t)n * Q4;
        f32x4 a0 = {0.f, 0.f, 0.f, 0.f}, a1 = a0, a2 = a0;
        #pragma unroll 7
        for (int q = 0; q < Q4; ++q) {
            f32x4 xv = xp[(size_t)q * IND];       // coalesced across lanes
            a0 += xv * gp[q];                      // wave-uniform broadcasts
            a1 += xv * gp[q + (size_t)NN * Q4];
            a2 += xv * gp[q + (size_t)2 * NN * Q4];
        }
        s[tid]           = a0.x + a0.y + a0.z + a0.w;
        s[IND + tid]     = a1.x + a1.y + a1.z + a1.w;
        s[2 * IND + tid] = a2.x + a2.y + a2.z + a2.w;
    }
    __syncthreads();
    // ---- phase 2: consume prefetch, continue W stream ----
    float4 acc = make_float4(0.f, 0.f, 0.f, 0.f);
#define CONS(wv, I) { float sv = s[(I)]; acc.x += sv * (wv).x; acc.y += sv * (wv).y; \
                      acc.z += sv * (wv).z; acc.w += sv * (wv).w; }
    CONS(w0, r)      CONS(w1, r + 4)  CONS(w2, r + 8)  CONS(w3, r + 12)
    CONS(w4, r + 16) CONS(w5, r + 20) CONS(w6, r + 24) CONS(w7, r + 28)
    CONS(w8, r + 32) CONS(w9, r + 36)
    #pragma unroll 8
    for (int i = r + 40; i < KI; i += 4) {
        f32x4 w = __builtin_nontemporal_load(Wp + (size_t)i * (HG / 4));
        float sv = s[i];
        acc.x += sv * w.x; acc.y += sv * w.y;
        acc.z += sv * w.z; acc.w += sv * w.w;
    }
#undef CONS
    red[r][c4 + 0] = acc.x; red[r][c4 + 1] = acc.y;
    red[r][c4 + 2] = acc.z; red[r][c4 + 3] = acc.w;
    __syncthreads();
    float a = bias[bn * HG + tid] + red[0][tid] + red[1][tid] + red[2][tid] + red[3][tid];
    float g = 1.0f / (1.0f + expf(-a));
    if (tid < HID) {
        z_out[bn * HID + tid] = g;                    // z
    } else {
        int hh = tid - HID;                           // r gate -> candidate elem at m=n
        int q = n >> 2, e = n & 3;
        xT2[(((size_t)b * Q4 + q) * IND + 2 + hh) * 4 + e] = g * h[bn * HID + hh];
    }
}

// K2: fused gcn2 + update, same prefetch structure.
__global__ __launch_bounds__(128) void update_fused(const float* __restrict__ G_p,
                                                    const float* __restrict__ xT2,
                                                    const float* __restrict__ W,
                                                    const float* __restrict__ bias,
                                                    const float* __restrict__ z,
                                                    const float* __restrict__ h,
                                                    float* __restrict__ out) {
    __shared__ float s[KI];
    __shared__ float red[8][HID];
    const int bn  = blockIdx.x;
    const int b   = bn / NN;
    const int n   = bn % NN;
    const int tid = threadIdx.x;
    const int r   = tid >> 4;
    const int c4  = (tid & 15) * 4;
    const f32x4* Wp = (const f32x4*)(W + (size_t)bn * KI * HID + c4);
    // ---- issue W prefetch ----
    f32x4 w0 = __builtin_nontemporal_load(Wp + (size_t)(r +  0) * (HID / 4));
    f32x4 w1 = __builtin_nontemporal_load(Wp + (size_t)(r +  8) * (HID / 4));
    f32x4 w2 = __builtin_nontemporal_load(Wp + (size_t)(r + 16) * (HID / 4));
    f32x4 w3 = __builtin_nontemporal_load(Wp + (size_t)(r + 24) * (HID / 4));
    f32x4 w4 = __builtin_nontemporal_load(Wp + (size_t)(r + 32) * (HID / 4));
    f32x4 w5 = __builtin_nontemporal_load(Wp + (size_t)(r + 40) * (HID / 4));
    f32x4 w6 = __builtin_nontemporal_load(Wp + (size_t)(r + 48) * (HID / 4));
    f32x4 w7 = __builtin_nontemporal_load(Wp + (size_t)(r + 56) * (HID / 4));
    f32x4 w8 = __builtin_nontemporal_load(Wp + (size_t)(r + 64) * (HID / 4));
    f32x4 w9 = __builtin_nontemporal_load(Wp + (size_t)(r + 72) * (HID / 4));
    // ---- phase 1 ----
    if (tid < IND) {
        const f32x4* xp = (const f32x4*)xT2 + (size_t)b * (Q4 * IND) + tid;
        const f32x4* gp = (const f32x4*)G_p + (size_t)n * Q4;
        f32x4 a0 = {0.f, 0.f, 0.f, 0.f}, a1 = a0, a2 = a0;
        #pragma unroll 7
        for (int q = 0; q < Q4; ++q) {
            f32x4 xv = xp[(size_t)q * IND];
            a0 += xv * gp[q];
            a1 += xv * gp[q + (size_t)NN * Q4];
            a2 += xv * gp[q + (size_t)2 * NN * Q4];
        }
        s[tid]           = a0.x + a0.y + a0.z + a0.w;
        s[IND + tid]     = a1.x + a1.y + a1.z + a1.w;
        s[2 * IND + tid] = a2.x + a2.y + a2.z + a2.w;
    }
    __syncthreads();
    // ---- phase 2 ----
    float4 acc = make_float4(0.f, 0.f, 0.f, 0.f);
#define CONS(wv, I) { float sv = s[(I)]; acc.x += sv * (wv).x; acc.y += sv * (wv).y; \
                      acc.z += sv * (wv).z; acc.w += sv * (wv).w; }
    CONS(w0, r)      CONS(w1, r + 8)  CONS(w2, r + 16) CONS(w3, r + 24)
    CONS(w4, r + 32) CONS(w5, r + 40) CONS(w6, r + 48) CONS(w7, r + 56)
    CONS(w8, r + 64) CONS(w9, r + 72)
    #pragma unroll 8
    for (int i = r + 80; i < KI; i += 8) {
        f32x4 w = __builtin_nontemporal_load(Wp + (size_t)i * (HID / 4));
        float sv = s[i];
        acc.x += sv * w.x; acc.y += sv * w.y;
        acc.z += sv * w.z; acc.w += sv * w.w;
    }
#undef CONS
    red[r][c4 + 0] = acc.x; red[r][c4 + 1] = acc.y;
    red[r][c4 + 2] = acc.z; red[r][c4 + 3] = acc.w;
    __syncthreads();
    if (tid < HID) {
        float a = bias[bn * HID + tid];
        #pragma unroll
        for (int rr = 0; rr < 8; ++rr) a += red[rr][tid];
        float nn = tanhf(a);
        float zz = z[bn * HID + tid];
        float hv = h[bn * HID + tid];
        out[bn * HID + tid] = zz * nn + (1.f - zz) * hv;
    }
}

extern "C" void kernel_launch(void* const* d_in, const int* in_sizes, int n_in,
                              void* d_out, int out_size, void* d_ws, size_t ws_size,
                              hipStream_t stream) {
    const float* G  = (const float*)d_in[0];
    const float* xt = (const float*)d_in[1];
    const float* h  = (const float*)d_in[2];
    const float* Wg = (const float*)d_in[3];
    const float* bg = (const float*)d_in[4];
    const float* Wu = (const float*)d_in[5];
    const float* bu = (const float*)d_in[6];
    float* out = (float*)d_out;

    float* ws   = (float*)d_ws;
    float* G_p  = ws + OFF_GP;
    float* x1   = ws + OFF_X1;
    float* x2   = ws + OFF_X2;
    float* z    = ws + OFF_Z;

    const int totPrep = SZ_GP + SZ_X + SZ_X2I;
    prep_kernel<<<(totPrep + 255) / 256, 256, 0, stream>>>(G, xt, h, G_p, x1, x2);

    gate_fused<<<NB * NN, 128, 0, stream>>>(G_p, x1, Wg, bg, h, z, x2);

    update_fused<<<NB * NN, 128, 0, stream>>>(G_p, x2, Wu, bu, z, h, out);
}